// Round 1
// baseline (316.560 us; speedup 1.0000x reference)
//
#include <hip/hip_runtime.h>

#define NCLASS 100
#define HID    768
#define BATCH  512
#define SG     8
#define HSPLIT 4

// ---------------------------------------------------------------------------
// Deterministic per-class sample list build (wave 0 of each block).
// slist gets the sample indices of class c in ascending order; scnt the count.
// ---------------------------------------------------------------------------
__device__ __forceinline__ void build_list(const int* __restrict__ y, int c,
                                           int* slist, int* scnt, int t) {
    if (t < 64) {
        int n = 0;
        for (int r = 0; r < BATCH / 64; ++r) {
            const int b = r * 64 + t;
            const bool hit = (y[b] == c);
            const unsigned long long mask = __ballot(hit);
            if (hit) {
                const int pos = n + __popcll(mask & ((1ull << t) - 1ull));
                slist[pos] = b;
            }
            n += __popcll(mask);
        }
        if (t == 0) *scnt = n;
    }
}

// ---------------------------------------------------------------------------
// Kernel 1: T[b,j] = sum_h x[b,h] * Mt[c,h,j], written as 4 h-partials.
// Mt[h,j] = (h<j) ? M[h,j]+1e-3 : (h==j) ? max(M[h,h],1e-3) : 1e-3.
// The 1e-3 parts are handled analytically: only strict-upper M + diag is read.
// grid = (100 classes, 4 h-splits); block = 256 threads; thread owns cols
// {t, t+256, t+512} and all SG samples of the current group.
// ---------------------------------------------------------------------------
__global__ __launch_bounds__(256, 2) void k1(
    const float* __restrict__ x, const int* __restrict__ y,
    const float* __restrict__ M, float* __restrict__ Tp)
{
    const int c    = blockIdx.x;
    const int hpar = blockIdx.y;
    const int t    = threadIdx.x;

    __shared__ int   slist[BATCH];
    __shared__ int   scnt;
    __shared__ float xs[SG][772];
    __shared__ float wsum[4][SG];

    build_list(y, c, slist, &scnt, t);
    __syncthreads();
    const int cnt = scnt;
    if (cnt == 0) return;

    const float* __restrict__ Mc = M + (size_t)c * HID * HID;
    const int j0 = t, j1 = t + 256, j2 = t + 512;

    for (int g0 = 0; g0 < cnt; g0 += SG) {
        const int gs = min(SG, cnt - g0);
        __syncthreads();   // protect xs/wsum reuse across groups
        // stage x rows of this sample group (duplicate row for s>=gs: discarded)
        for (int s = 0; s < SG; ++s) {
            const int b = slist[g0 + (s < gs ? s : 0)];
            if (t < HID / 4)
                *(float4*)&xs[s][t * 4] = ((const float4*)(x + (size_t)b * HID))[t];
        }
        __syncthreads();

        if (hpar == 0) {   // row sums of x for the analytic 1e-3 term
            for (int s = 0; s < SG; ++s) {
                float p = xs[s][t] + xs[s][t + 256] + xs[s][t + 512];
                #pragma unroll
                for (int off = 32; off > 0; off >>= 1) p += __shfl_xor(p, off);
                if ((t & 63) == 0) wsum[t >> 6][s] = p;
            }
        }

        float acc0[SG], acc1[SG], acc2[SG];
        #pragma unroll
        for (int s = 0; s < SG; ++s) { acc0[s] = 0.f; acc1[s] = 0.f; acc2[s] = 0.f; }

        // h-rows of this split: h = 4*hpar + 16*gi + u
        for (int gi = 0; gi < 48; ++gi) {
            const int h0 = 4 * hpar + 16 * gi;
            float m0[4], m1[4], m2[4];
            #pragma unroll
            for (int u = 0; u < 4; ++u) {
                const int h = h0 + u;
                const float* __restrict__ row = Mc + (size_t)h * HID;
                const float v0 = (h <= j0) ? row[j0] : 0.f;
                const float v1 = (h <= j1) ? row[j1] : 0.f;
                const float v2 = (h <= j2) ? row[j2] : 0.f;
                m0[u] = (h < j0) ? v0 : ((h == j0) ? fmaxf(v0, 1e-3f) : 0.f);
                m1[u] = (h < j1) ? v1 : ((h == j1) ? fmaxf(v1, 1e-3f) : 0.f);
                m2[u] = (h < j2) ? v2 : ((h == j2) ? fmaxf(v2, 1e-3f) : 0.f);
            }
            #pragma unroll
            for (int s = 0; s < SG; ++s) {
                const float4 xv = *(const float4*)&xs[s][h0];
                acc0[s] = fmaf(xv.x, m0[0], acc0[s]);
                acc0[s] = fmaf(xv.y, m0[1], acc0[s]);
                acc0[s] = fmaf(xv.z, m0[2], acc0[s]);
                acc0[s] = fmaf(xv.w, m0[3], acc0[s]);
                acc1[s] = fmaf(xv.x, m1[0], acc1[s]);
                acc1[s] = fmaf(xv.y, m1[1], acc1[s]);
                acc1[s] = fmaf(xv.z, m1[2], acc1[s]);
                acc1[s] = fmaf(xv.w, m1[3], acc1[s]);
                acc2[s] = fmaf(xv.x, m2[0], acc2[s]);
                acc2[s] = fmaf(xv.y, m2[1], acc2[s]);
                acc2[s] = fmaf(xv.z, m2[2], acc2[s]);
                acc2[s] = fmaf(xv.w, m2[3], acc2[s]);
            }
        }
        __syncthreads();   // wsum ready for all threads

        if (hpar == 0) {
            for (int s = 0; s < gs; ++s) {
                const float Xs = wsum[0][s] + wsum[1][s] + wsum[2][s] + wsum[3][s];
                acc0[s] += 1e-3f * (Xs - xs[s][j0]);
                acc1[s] += 1e-3f * (Xs - xs[s][j1]);
                acc2[s] += 1e-3f * (Xs - xs[s][j2]);
            }
        }
        float* Tpp = Tp + (size_t)hpar * (BATCH * HID);
        for (int s = 0; s < gs; ++s) {
            float* Tr = Tpp + (size_t)slist[g0 + s] * HID;
            Tr[j0] = acc0[s];
            Tr[j1] = acc1[s];
            Tr[j2] = acc2[s];
        }
    }
}

// ---------------------------------------------------------------------------
// Kernel 2: out[b,k] = sum_j T[b,j] * Mt[c,k,j].
// Reduction is over M columns -> stage 256x32 M tiles in LDS with XOR swizzle
// (col4 ^= (row>>2)&7) so ds_read_b128 across 64 rows is conflict-free.
// grid = (100 classes, 3 k-chunks of 256); block = 256 threads =
// 4 sample-pairs x 64 row-quads; thread tile = 2 samples x 4 rows.
// ---------------------------------------------------------------------------
__global__ __launch_bounds__(256, 2) void k2(
    const int* __restrict__ y, const float* __restrict__ M,
    const float* __restrict__ Tp, float* __restrict__ out)
{
    const int c  = blockIdx.x;
    const int kc = blockIdx.y;
    const int t  = threadIdx.x;
    const int k0 = kc * 256;

    __shared__ int   slist[BATCH];
    __shared__ int   scnt;
    __shared__ float Ts[SG][772];
    __shared__ float Mt_[256 * 32];
    __shared__ float wsum[4][SG];

    build_list(y, c, slist, &scnt, t);
    __syncthreads();
    const int cnt = scnt;
    if (cnt == 0) return;

    const float* __restrict__ Mc = M + (size_t)c * HID * HID;
    const int kg  = t & 63;     // 64 row-quads
    const int sg  = t >> 6;     // 4 sample-pairs
    const int sA  = sg * 2, sB = sg * 2 + 1;
    const int jt0 = k0 >> 5;

    for (int g0 = 0; g0 < cnt; g0 += SG) {
        const int gs = min(SG, cnt - g0);
        __syncthreads();
        // stage T rows (sum of the 4 h-partials)
        for (int s = 0; s < SG; ++s) {
            const size_t b = (size_t)slist[g0 + (s < gs ? s : 0)];
            if (t < HID / 4) {
                const float4 a0 = ((const float4*)(Tp + b * HID))[t];
                const float4 a1 = ((const float4*)(Tp + ((size_t)BATCH + b) * HID))[t];
                const float4 a2 = ((const float4*)(Tp + ((size_t)2 * BATCH + b) * HID))[t];
                const float4 a3 = ((const float4*)(Tp + ((size_t)3 * BATCH + b) * HID))[t];
                float4 r;
                r.x = (a0.x + a1.x) + (a2.x + a3.x);
                r.y = (a0.y + a1.y) + (a2.y + a3.y);
                r.z = (a0.z + a1.z) + (a2.z + a3.z);
                r.w = (a0.w + a1.w) + (a2.w + a3.w);
                *(float4*)&Ts[s][t * 4] = r;
            }
        }
        __syncthreads();
        // T row sums for the analytic 1e-3 term
        for (int s = 0; s < SG; ++s) {
            float p = Ts[s][t] + Ts[s][t + 256] + Ts[s][t + 512];
            #pragma unroll
            for (int off = 32; off > 0; off >>= 1) p += __shfl_xor(p, off);
            if ((t & 63) == 0) wsum[t >> 6][s] = p;
        }

        float accA[4], accB[4];
        #pragma unroll
        for (int q = 0; q < 4; ++q) { accA[q] = 0.f; accB[q] = 0.f; }

        for (int jt = jt0; jt < 24; ++jt) {
            const int jb0 = jt * 32;
            __syncthreads();   // previous tile compute done (also orders wsum)
            #pragma unroll
            for (int w = 0; w < 8; ++w) {
                const int i  = t + 256 * w;
                const int r  = i >> 3, q4 = i & 7;
                const int kr = k0 + r;
                if (jb0 + 31 >= kr) {   // skip fully-below-diagonal row segments
                    const float4 v = *(const float4*)(Mc + (size_t)kr * HID + jb0 + q4 * 4);
                    *(float4*)&Mt_[r * 32 + ((q4 ^ ((r >> 2) & 7)) << 2)] = v;
                }
            }
            __syncthreads();

            const bool fast  = (jb0 > k0 + 255);   // tile strictly above diagonal
            const int  kbase = k0 + (kg << 2);
            if (fast) {
                #pragma unroll
                for (int q4 = 0; q4 < 8; ++q4) {
                    const float4 ta = *(const float4*)&Ts[sA][jb0 + q4 * 4];
                    const float4 tb = *(const float4*)&Ts[sB][jb0 + q4 * 4];
                    #pragma unroll
                    for (int kk = 0; kk < 4; ++kk) {
                        const int r = (kg << 2) + kk;
                        const float4 mv = *(const float4*)&Mt_[r * 32 + ((q4 ^ (kg & 7)) << 2)];
                        accA[kk] = fmaf(ta.x, mv.x, accA[kk]);
                        accA[kk] = fmaf(ta.y, mv.y, accA[kk]);
                        accA[kk] = fmaf(ta.z, mv.z, accA[kk]);
                        accA[kk] = fmaf(ta.w, mv.w, accA[kk]);
                        accB[kk] = fmaf(tb.x, mv.x, accB[kk]);
                        accB[kk] = fmaf(tb.y, mv.y, accB[kk]);
                        accB[kk] = fmaf(tb.z, mv.z, accB[kk]);
                        accB[kk] = fmaf(tb.w, mv.w, accB[kk]);
                    }
                }
            } else if (kbase <= jb0 + 31) {   // diagonal-crossing tile
                #pragma unroll
                for (int q4 = 0; q4 < 8; ++q4) {
                    const int jb = jb0 + q4 * 4;
                    const float4 ta = *(const float4*)&Ts[sA][jb0 + q4 * 4];
                    const float4 tb = *(const float4*)&Ts[sB][jb0 + q4 * 4];
                    #pragma unroll
                    for (int kk = 0; kk < 4; ++kk) {
                        const int r = (kg << 2) + kk;
                        const int k = k0 + r;
                        const float4 mv = *(const float4*)&Mt_[r * 32 + ((q4 ^ (kg & 7)) << 2)];
                        const float mx = (jb + 0 > k) ? mv.x : ((jb + 0 == k) ? fmaxf(mv.x, 1e-3f) : 0.f);
                        const float my = (jb + 1 > k) ? mv.y : ((jb + 1 == k) ? fmaxf(mv.y, 1e-3f) : 0.f);
                        const float mz = (jb + 2 > k) ? mv.z : ((jb + 2 == k) ? fmaxf(mv.z, 1e-3f) : 0.f);
                        const float mw = (jb + 3 > k) ? mv.w : ((jb + 3 == k) ? fmaxf(mv.w, 1e-3f) : 0.f);
                        accA[kk] = fmaf(ta.x, mx, accA[kk]);
                        accA[kk] = fmaf(ta.y, my, accA[kk]);
                        accA[kk] = fmaf(ta.z, mz, accA[kk]);
                        accA[kk] = fmaf(ta.w, mw, accA[kk]);
                        accB[kk] = fmaf(tb.x, mx, accB[kk]);
                        accB[kk] = fmaf(tb.y, my, accB[kk]);
                        accB[kk] = fmaf(tb.z, mz, accB[kk]);
                        accB[kk] = fmaf(tb.w, mw, accB[kk]);
                    }
                }
            }
        }

        // epilogue: analytic term + store
        const int kb = k0 + (kg << 2);
        if (sA < gs) {
            const float ts = wsum[0][sA] + wsum[1][sA] + wsum[2][sA] + wsum[3][sA];
            float4 o;
            o.x = accA[0] + 1e-3f * (ts - Ts[sA][kb + 0]);
            o.y = accA[1] + 1e-3f * (ts - Ts[sA][kb + 1]);
            o.z = accA[2] + 1e-3f * (ts - Ts[sA][kb + 2]);
            o.w = accA[3] + 1e-3f * (ts - Ts[sA][kb + 3]);
            *(float4*)(out + (size_t)slist[g0 + sA] * HID + kb) = o;
        }
        if (sB < gs) {
            const float ts = wsum[0][sB] + wsum[1][sB] + wsum[2][sB] + wsum[3][sB];
            float4 o;
            o.x = accB[0] + 1e-3f * (ts - Ts[sB][kb + 0]);
            o.y = accB[1] + 1e-3f * (ts - Ts[sB][kb + 1]);
            o.z = accB[2] + 1e-3f * (ts - Ts[sB][kb + 2]);
            o.w = accB[3] + 1e-3f * (ts - Ts[sB][kb + 3]);
            *(float4*)(out + (size_t)slist[g0 + sB] * HID + kb) = o;
        }
    }
}

extern "C" void kernel_launch(void* const* d_in, const int* in_sizes, int n_in,
                              void* d_out, int out_size, void* d_ws, size_t ws_size,
                              hipStream_t stream) {
    const float* x = (const float*)d_in[0];
    const int*   y = (const int*)d_in[1];
    const float* M = (const float*)d_in[2];
    float* out = (float*)d_out;
    float* Tp  = (float*)d_ws;   // 4 * 512 * 768 floats = 6.0 MiB of scratch

    k1<<<dim3(NCLASS, HSPLIT), 256, 0, stream>>>(x, y, M, Tp);
    k2<<<dim3(NCLASS, 3),      256, 0, stream>>>(y, M, Tp, out);
}

// Round 2
// 240.684 us; speedup vs baseline: 1.3152x; 1.3152x over previous
//
#include <hip/hip_runtime.h>

#define NCLASS 100
#define HID    768
#define BATCH  512
#define SG     8
#define NSPLIT 4
#define PPS    12      // panels per split (48 total / 4 splits)
#define PW     16      // panel width in columns

// Deterministic per-class sample list (wave 0).
__device__ __forceinline__ void build_list(const int* __restrict__ y, int c,
                                           int* slist, int* scnt, int t) {
    if (t < 64) {
        int n = 0;
        for (int r = 0; r < BATCH / 64; ++r) {
            const int b = r * 64 + t;
            const bool hit = (y[b] == c);
            const unsigned long long mask = __ballot(hit);
            if (hit) slist[n + __popcll(mask & ((1ull << t) - 1ull))] = b;
            n += __popcll(mask);
        }
        if (t == 0) *scnt = n;
    }
}

// ---------------------------------------------------------------------------
// Fused one-pass kernel. Block (c, split) owns panels p = split + 4i.
// Per panel J=[16p,16p+16):
//   phase 1: t_j = sum_{h<j} x_h M[h,j] + d_j x_j + 1e-3 (X - x_j)
//            (rows h streamed float4 from HBM; outer-product into regs;
//             shuffle + small-LDS reduce)
//   phase 2: P += sum_{j in J, j>k} M[k,j] t_j  (same rows, now L2-hot,
//            row-major float4; t_J hoisted to registers)
//   own-diag: += (d_k - 1e-3) t_k for k in J;  epilogue adds 1e-3 * sum t_j.
// P[split][b][k] partials in ws (4*512*768*4 = 6 MiB, proven-safe size).
// ---------------------------------------------------------------------------
__global__ __launch_bounds__(512, 4) void fused(
    const float* __restrict__ x, const int* __restrict__ y,
    const float* __restrict__ M, float* __restrict__ P)
{
    const int c     = blockIdx.x;
    const int split = blockIdx.y;
    const int t     = threadIdx.x;

    __shared__ int   slist[BATCH];
    __shared__ int   scnt;
    __shared__ float xs[SG][HID];          // 24 KB
    __shared__ float Xs[SG];
    __shared__ float red[8][4][4][SG];     // [wave][jq][jj][s] 4 KB
    __shared__ float t_lds[PW][SG];
    __shared__ float d_lds[PW];
    __shared__ float Tt[SG];

    build_list(y, c, slist, &scnt, t);
    __syncthreads();
    const int cnt = scnt;
    if (cnt == 0) return;

    const float* __restrict__ Mc = M + (size_t)c * HID * HID;
    const int hg = t >> 2, jq = t & 3;     // phase-1 mapping: 128 row-groups x 4 col-quads
    const int wv = t >> 6, ln = t & 63;
    const int kg = t >> 3, sp = t & 7;     // phase-2 mapping: 64 k-groups x 8 samples

    for (int g0 = 0; g0 < cnt; g0 += SG) {
        const int gs = min(SG, cnt - g0);
        __syncthreads();                   // previous group fully done
        // stage x rows: wave wv stages sample wv
        {
            const int b = slist[g0 + (wv < gs ? wv : 0)];
            const float4* xr = (const float4*)(x + (size_t)b * HID);
            *(float4*)&xs[wv][(ln      ) * 4] = xr[ln];
            *(float4*)&xs[wv][(ln +  64) * 4] = xr[ln +  64];
            *(float4*)&xs[wv][(ln + 128) * 4] = xr[ln + 128];
            float pX = 0.f;
            #pragma unroll
            for (int q = 0; q < 3; ++q) {
                const float4 v = *(float4*)&xs[wv][(ln + 64 * q) * 4];
                pX += (v.x + v.y) + (v.z + v.w);
            }
            #pragma unroll
            for (int off = 32; off; off >>= 1) pX += __shfl_xor(pX, off);
            if (ln == 0) Xs[wv] = pX;
        }
        float acc[PPS];
        #pragma unroll
        for (int m = 0; m < PPS; ++m) acc[m] = 0.f;
        if (t < SG) Tt[t] = 0.f;
        __syncthreads();                   // xs, Xs visible

        for (int pi = 0; pi < PPS; ++pi) {
            const int p    = split + pi * NSPLIT;
            const int col0 = p * PW;
            const int jmax = col0 + PW - 1;

            // ---- phase 1: partial t over this thread's rows ----
            float tp[4][SG];
            #pragma unroll
            for (int jj = 0; jj < 4; ++jj)
                #pragma unroll
                for (int s = 0; s < SG; ++s) tp[jj][s] = 0.f;

            for (int h = hg; h < col0 + PW; h += 128) {
                float4 mq = *(const float4*)(Mc + (size_t)h * HID + col0 + jq * 4);
                if (h >= col0) {           // diagonal panel rows: keep strictly h<j
                    const int hrel = h - col0;
                    if (4 * jq + 0 <= hrel) mq.x = 0.f;
                    if (4 * jq + 1 <= hrel) mq.y = 0.f;
                    if (4 * jq + 2 <= hrel) mq.z = 0.f;
                    if (4 * jq + 3 <= hrel) mq.w = 0.f;
                }
                #pragma unroll
                for (int s = 0; s < SG; ++s) {
                    const float xv = xs[s][h];
                    tp[0][s] = fmaf(xv, mq.x, tp[0][s]);
                    tp[1][s] = fmaf(xv, mq.y, tp[1][s]);
                    tp[2][s] = fmaf(xv, mq.z, tp[2][s]);
                    tp[3][s] = fmaf(xv, mq.w, tp[3][s]);
                }
            }
            // reduce the 16 row-groups within each wave (lane bits 2..5)
            #pragma unroll
            for (int m = 4; m <= 32; m <<= 1)
                #pragma unroll
                for (int jj = 0; jj < 4; ++jj)
                    #pragma unroll
                    for (int s = 0; s < SG; ++s)
                        tp[jj][s] += __shfl_xor(tp[jj][s], m);
            if (ln < 4) {
                #pragma unroll
                for (int jj = 0; jj < 4; ++jj)
                    #pragma unroll
                    for (int s = 0; s < SG; ++s)
                        red[wv][ln][jj][s] = tp[jj][s];
            }
            __syncthreads();               // red visible
            // finalize t_j (threads 0..127: j = t>>3, s = t&7)
            if (t < PW * SG) {
                const int j = t >> 3, s = t & 7;
                float u = 0.f;
                #pragma unroll
                for (int w = 0; w < 8; ++w) u += red[w][j >> 2][j & 3][s];
                const int jg = col0 + j;
                const float dj = fmaxf(Mc[(size_t)jg * HID + jg], 1e-3f);
                const float xj = xs[s][jg];
                t_lds[j][s] = u + dj * xj + 1e-3f * (Xs[s] - xj);
                if (s == 0) d_lds[j] = dj;
            }
            __syncthreads();               // t_lds, d_lds visible
            if (t < SG) {
                float a = 0.f;
                #pragma unroll
                for (int j = 0; j < PW; ++j) a += t_lds[j][t];
                Tt[t] += a;
            }

            // ---- phase 2: rank-1 updates, rows re-read from L2 ----
            float tReg[PW];
            #pragma unroll
            for (int j = 0; j < PW; ++j) tReg[j] = t_lds[j][sp];

            #pragma unroll
            for (int m = 0; m < PPS; ++m) {
                const int k = kg + 64 * m;
                if (k <= jmax) {
                    const float* rowk = Mc + (size_t)k * HID + col0;
                    float4 q0 = ((const float4*)rowk)[0];
                    float4 q1 = ((const float4*)rowk)[1];
                    float4 q2 = ((const float4*)rowk)[2];
                    float4 q3 = ((const float4*)rowk)[3];
                    float a = acc[m];
                    if (k >= col0) {       // diagonal panel: mask j<=k, add diag
                        const int krel = k - col0;
                        if ( 0 <= krel) q0.x = 0.f;
                        if ( 1 <= krel) q0.y = 0.f;
                        if ( 2 <= krel) q0.z = 0.f;
                        if ( 3 <= krel) q0.w = 0.f;
                        if ( 4 <= krel) q1.x = 0.f;
                        if ( 5 <= krel) q1.y = 0.f;
                        if ( 6 <= krel) q1.z = 0.f;
                        if ( 7 <= krel) q1.w = 0.f;
                        if ( 8 <= krel) q2.x = 0.f;
                        if ( 9 <= krel) q2.y = 0.f;
                        if (10 <= krel) q2.z = 0.f;
                        if (11 <= krel) q2.w = 0.f;
                        if (12 <= krel) q3.x = 0.f;
                        if (13 <= krel) q3.y = 0.f;
                        if (14 <= krel) q3.z = 0.f;
                        if (15 <= krel) q3.w = 0.f;
                        a += (d_lds[krel] - 1e-3f) * t_lds[krel][sp];
                    }
                    a = fmaf(q0.x, tReg[ 0], a);
                    a = fmaf(q0.y, tReg[ 1], a);
                    a = fmaf(q0.z, tReg[ 2], a);
                    a = fmaf(q0.w, tReg[ 3], a);
                    a = fmaf(q1.x, tReg[ 4], a);
                    a = fmaf(q1.y, tReg[ 5], a);
                    a = fmaf(q1.z, tReg[ 6], a);
                    a = fmaf(q1.w, tReg[ 7], a);
                    a = fmaf(q2.x, tReg[ 8], a);
                    a = fmaf(q2.y, tReg[ 9], a);
                    a = fmaf(q2.z, tReg[10], a);
                    a = fmaf(q2.w, tReg[11], a);
                    a = fmaf(q3.x, tReg[12], a);
                    a = fmaf(q3.y, tReg[13], a);
                    a = fmaf(q3.z, tReg[14], a);
                    a = fmaf(q3.w, tReg[15], a);
                    acc[m] = a;
                }
            }
            __syncthreads();               // t_lds reads done before next overwrite
        }

        // epilogue: add analytic 1e-3 * Tt and store this split's partial
        const float tt = 1e-3f * Tt[sp];
        if (sp < gs) {
            const int b = slist[g0 + sp];
            float* Pr = P + ((size_t)split * BATCH + b) * HID;
            #pragma unroll
            for (int m = 0; m < PPS; ++m) Pr[kg + 64 * m] = acc[m] + tt;
        }
    }
}

// out = sum of the 4 split partials
__global__ __launch_bounds__(256) void reduce_k(const float* __restrict__ P,
                                                float* __restrict__ out)
{
    const int i = blockIdx.x * 256 + threadIdx.x;      // float4 index, 98304 total
    const float4* p = (const float4*)P;
    const float4 a = p[i];
    const float4 b = p[i +     98304];
    const float4 c = p[i + 2 * 98304];
    const float4 d = p[i + 3 * 98304];
    float4 r;
    r.x = (a.x + b.x) + (c.x + d.x);
    r.y = (a.y + b.y) + (c.y + d.y);
    r.z = (a.z + b.z) + (c.z + d.z);
    r.w = (a.w + b.w) + (c.w + d.w);
    ((float4*)out)[i] = r;
}

extern "C" void kernel_launch(void* const* d_in, const int* in_sizes, int n_in,
                              void* d_out, int out_size, void* d_ws, size_t ws_size,
                              hipStream_t stream) {
    const float* x = (const float*)d_in[0];
    const int*   y = (const int*)d_in[1];
    const float* M = (const float*)d_in[2];
    float* out = (float*)d_out;
    float* P   = (float*)d_ws;   // 4 * 512 * 768 * 4 B = 6 MiB

    fused<<<dim3(NCLASS, NSPLIT), 512, 0, stream>>>(x, y, M, P);
    reduce_k<<<dim3(BATCH * HID / 4 / 256), 256, 0, stream>>>(P, out);
}

// Round 3
// 103.923 us; speedup vs baseline: 3.0461x; 2.3160x over previous
//
#include <hip/hip_runtime.h>

#define NCLASS 100
#define HID    768
#define BATCH  512
#define SG     8

// Deterministic per-class sample list (wave 0 of each block).
__device__ __forceinline__ void build_list(const int* __restrict__ y, int c,
                                           int* slist, int* scnt, int t) {
    if (t < 64) {
        int n = 0;
        for (int r = 0; r < BATCH / 64; ++r) {
            const int b = r * 64 + t;
            const bool hit = (y[b] == c);
            const unsigned long long mask = __ballot(hit);
            if (hit) slist[n + __popcll(mask & ((1ull << t) - 1ull))] = b;
            n += __popcll(mask);
        }
        if (t == 0) *scnt = n;
    }
}

// ---------------------------------------------------------------------------
// Kernel A: t[b, j] for j in panel J=[16p,16p+16), b in class c.
//   t_j = sum_{h<j} x_h M[h,j] + d_j x_j + 1e-3 (X - x_j),  d_j=max(M[j,j],1e-3)
// Column strip rows 0..col0+15 read as 64B-coalesced float4 quads.
// Thread map: hg = t>>2 (64 row-groups), jq = t&3 (4 col-quads).
// ---------------------------------------------------------------------------
__global__ __launch_bounds__(256, 4) void kA(
    const float* __restrict__ x, const int* __restrict__ y,
    const float* __restrict__ M, float* __restrict__ T)
{
    const int c    = blockIdx.x;
    const int p    = blockIdx.y;
    const int t    = threadIdx.x;
    const int col0 = p * 16;

    __shared__ int   slist[BATCH];
    __shared__ int   scnt;
    __shared__ float xs[SG][HID];
    __shared__ float Xs[SG];
    __shared__ float red[4][4][4][SG];   // [wave][jq][jj][s]

    build_list(y, c, slist, &scnt, t);
    __syncthreads();
    const int cnt = scnt;
    if (cnt == 0) return;

    const float* __restrict__ Mc = M + (size_t)c * HID * HID;
    const int wv = t >> 6, ln = t & 63;
    const int hg = t >> 2, jq = t & 3;

    for (int g0 = 0; g0 < cnt; g0 += SG) {
        const int gs = min(SG, cnt - g0);
        __syncthreads();                      // previous group fully done
        // stage x rows: wave wv stages samples 2wv, 2wv+1; also row-sums X
        #pragma unroll
        for (int ss = 0; ss < 2; ++ss) {
            const int s = 2 * wv + ss;
            const int b = slist[g0 + (s < gs ? s : 0)];
            const float4* xr = (const float4*)(x + (size_t)b * HID);
            const float4 v0 = xr[ln], v1 = xr[ln + 64], v2 = xr[ln + 128];
            *(float4*)&xs[s][ln * 4]       = v0;
            *(float4*)&xs[s][ln * 4 + 256] = v1;
            *(float4*)&xs[s][ln * 4 + 512] = v2;
            float pX = ((v0.x + v0.y) + (v0.z + v0.w))
                     + ((v1.x + v1.y) + (v1.z + v1.w))
                     + ((v2.x + v2.y) + (v2.z + v2.w));
            #pragma unroll
            for (int off = 32; off; off >>= 1) pX += __shfl_xor(pX, off);
            if (ln == 0) Xs[s] = pX;
        }
        __syncthreads();                      // xs, Xs visible

        float tp[4][SG];
        #pragma unroll
        for (int jj = 0; jj < 4; ++jj)
            #pragma unroll
            for (int s = 0; s < SG; ++s) tp[jj][s] = 0.f;

        for (int h = hg; h < col0 + 16; h += 64) {
            float4 mq = *(const float4*)(Mc + (size_t)h * HID + col0 + jq * 4);
            if (h >= col0) {                  // diagonal panel rows: strict h<j
                const int hrel = h - col0;
                if (4 * jq + 0 <= hrel) mq.x = 0.f;
                if (4 * jq + 1 <= hrel) mq.y = 0.f;
                if (4 * jq + 2 <= hrel) mq.z = 0.f;
                if (4 * jq + 3 <= hrel) mq.w = 0.f;
            }
            #pragma unroll
            for (int s = 0; s < SG; ++s) {
                const float xv = xs[s][h];
                tp[0][s] = fmaf(xv, mq.x, tp[0][s]);
                tp[1][s] = fmaf(xv, mq.y, tp[1][s]);
                tp[2][s] = fmaf(xv, mq.z, tp[2][s]);
                tp[3][s] = fmaf(xv, mq.w, tp[3][s]);
            }
        }
        // reduce over the 16 row-groups within each wave (lane bits 2..5)
        #pragma unroll
        for (int m = 4; m <= 32; m <<= 1)
            #pragma unroll
            for (int jj = 0; jj < 4; ++jj)
                #pragma unroll
                for (int s = 0; s < SG; ++s)
                    tp[jj][s] += __shfl_xor(tp[jj][s], m);
        if (ln < 4) {
            #pragma unroll
            for (int jj = 0; jj < 4; ++jj)
                #pragma unroll
                for (int s = 0; s < SG; ++s)
                    red[wv][ln][jj][s] = tp[jj][s];
        }
        __syncthreads();                      // red visible
        if (t < 16 * SG) {                    // j = t>>3, s = t&7
            const int j = t >> 3, s = t & 7;
            const float u = ((red[0][j >> 2][j & 3][s] + red[1][j >> 2][j & 3][s])
                           + (red[2][j >> 2][j & 3][s] + red[3][j >> 2][j & 3][s]));
            const int jg = col0 + j;
            const float dj = fmaxf(Mc[(size_t)jg * HID + jg], 1e-3f);
            const float xj = xs[s][jg];
            if (s < gs)
                T[(size_t)slist[g0 + s] * HID + jg] = u + dj * xj + 1e-3f * (Xs[s] - xj);
        }
    }
}

// ---------------------------------------------------------------------------
// Kernel B: out[b, k] for k in panel K=[16q,16q+16), b in class c.
//   out_k = sum_{j>k} M[k,j] t_j + d_k t_k + 1e-3 (Tt - t_k)
// Row strip k in K, j >= k0 read 256B-coalesced.
// Thread map: kl = t>>4 (16 rows), cg = t&15 (16 col-quads).
// ---------------------------------------------------------------------------
__global__ __launch_bounds__(256, 4) void kB(
    const int* __restrict__ y, const float* __restrict__ M,
    const float* __restrict__ T, float* __restrict__ out)
{
    const int c  = blockIdx.x;
    const int q  = blockIdx.y;
    const int t  = threadIdx.x;
    const int k0 = q * 16;

    __shared__ int   slist[BATCH];
    __shared__ int   scnt;
    __shared__ float ts[SG][HID];
    __shared__ float Tt[SG];

    build_list(y, c, slist, &scnt, t);
    __syncthreads();
    const int cnt = scnt;
    if (cnt == 0) return;

    const float* __restrict__ Mc = M + (size_t)c * HID * HID;
    const int wv = t >> 6, ln = t & 63;
    const int kl = t >> 4, cg = t & 15;
    const int k  = k0 + kl;
    const float dk = fmaxf(Mc[(size_t)k * HID + k], 1e-3f);

    for (int g0 = 0; g0 < cnt; g0 += SG) {
        const int gs = min(SG, cnt - g0);
        __syncthreads();                      // previous group fully done
        // stage t rows: wave wv stages samples 2wv, 2wv+1; also row-sums Tt
        #pragma unroll
        for (int ss = 0; ss < 2; ++ss) {
            const int s = 2 * wv + ss;
            const int b = slist[g0 + (s < gs ? s : 0)];
            const float4* tr = (const float4*)(T + (size_t)b * HID);
            const float4 v0 = tr[ln], v1 = tr[ln + 64], v2 = tr[ln + 128];
            *(float4*)&ts[s][ln * 4]       = v0;
            *(float4*)&ts[s][ln * 4 + 256] = v1;
            *(float4*)&ts[s][ln * 4 + 512] = v2;
            float pT = ((v0.x + v0.y) + (v0.z + v0.w))
                     + ((v1.x + v1.y) + (v1.z + v1.w))
                     + ((v2.x + v2.y) + (v2.z + v2.w));
            #pragma unroll
            for (int off = 32; off; off >>= 1) pT += __shfl_xor(pT, off);
            if (ln == 0) Tt[s] = pT;
        }
        __syncthreads();                      // ts, Tt visible

        float acc[SG];
        #pragma unroll
        for (int s = 0; s < SG; ++s) acc[s] = 0.f;

        for (int jb = k0; jb < HID; jb += 64) {
            const int j0 = jb + cg * 4;
            if (j0 < HID) {
                float4 mq = *(const float4*)(Mc + (size_t)k * HID + j0);
                if (jb == k0) {               // diag-crossing chunk: keep j>k only
                    if (j0 + 0 <= k) mq.x = 0.f;
                    if (j0 + 1 <= k) mq.y = 0.f;
                    if (j0 + 2 <= k) mq.z = 0.f;
                    if (j0 + 3 <= k) mq.w = 0.f;
                }
                #pragma unroll
                for (int s = 0; s < SG; ++s) {
                    const float4 tv = *(const float4*)&ts[s][j0];
                    acc[s] = fmaf(mq.x, tv.x, acc[s]);
                    acc[s] = fmaf(mq.y, tv.y, acc[s]);
                    acc[s] = fmaf(mq.z, tv.z, acc[s]);
                    acc[s] = fmaf(mq.w, tv.w, acc[s]);
                }
            }
        }
        // reduce over the 16 col-quads (lane bits 0..3)
        #pragma unroll
        for (int m = 1; m <= 8; m <<= 1)
            #pragma unroll
            for (int s = 0; s < SG; ++s)
                acc[s] += __shfl_xor(acc[s], m);
        if (cg == 0) {
            for (int s = 0; s < gs; ++s) {
                const float tk = ts[s][k];
                out[(size_t)slist[g0 + s] * HID + k] =
                    acc[s] + dk * tk + 1e-3f * (Tt[s] - tk);
            }
        }
    }
}

extern "C" void kernel_launch(void* const* d_in, const int* in_sizes, int n_in,
                              void* d_out, int out_size, void* d_ws, size_t ws_size,
                              hipStream_t stream) {
    const float* x = (const float*)d_in[0];
    const int*   y = (const int*)d_in[1];
    const float* M = (const float*)d_in[2];
    float* out = (float*)d_out;
    float* T   = (float*)d_ws;   // 512 * 768 * 4 B = 1.5 MiB scratch

    kA<<<dim3(NCLASS, HID / 16), 256, 0, stream>>>(x, y, M, T);
    kB<<<dim3(NCLASS, HID / 16), 256, 0, stream>>>(y, M, T, out);
}

// Round 4
// 87.049 us; speedup vs baseline: 3.6366x; 1.1938x over previous
//
#include <hip/hip_runtime.h>

#define NCLASS 100
#define HID    768
#define BATCH  512
#define SG     8
#define NPAN   12      // 12 panels of 64 columns/rows

// Deterministic per-class sample list (wave 0 of each block).
__device__ __forceinline__ void build_list(const int* __restrict__ y, int c,
                                           int* slist, int* scnt, int t) {
    if (t < 64) {
        int n = 0;
        for (int r = 0; r < BATCH / 64; ++r) {
            const int b = r * 64 + t;
            const bool hit = (y[b] == c);
            const unsigned long long mask = __ballot(hit);
            if (hit) slist[n + __popcll(mask & ((1ull << t) - 1ull))] = b;
            n += __popcll(mask);
        }
        if (t == 0) *scnt = n;
    }
}

// ---------------------------------------------------------------------------
// Kernel A: t[b, j] for j in 64-col panel J=[64g, 64g+64), b in class c.
//   t_j = sum_{h<j} x_h M[h,j] + d_j x_j + 1e-3 (X - x_j), d_j=max(M[j,j],1e-3)
// Column strip rows 0..col0+63, each row read as 256 B contiguous (16 float4).
// Thread map: hg = t>>4 (16 rows/chunk), jq = t&15 (16 col-quads).
// Big panels (g=11) dispatch first to avoid a straggler tail.
// ---------------------------------------------------------------------------
__global__ __launch_bounds__(256, 4) void kA(
    const float* __restrict__ x, const int* __restrict__ y,
    const float* __restrict__ M, float* __restrict__ T)
{
    const int c    = blockIdx.x;
    const int g    = (NPAN - 1) - blockIdx.y;   // 11, 10, ... 0
    const int t    = threadIdx.x;
    const int col0 = g * 64;

    __shared__ int   slist[BATCH];
    __shared__ int   scnt;
    __shared__ float xs[SG][HID];         // 24 KB
    __shared__ float Xs[SG];
    __shared__ float red[4][16][4][SG];   // [wave][jq][jj][s]  8 KB
    __shared__ float dj_lds[64];

    build_list(y, c, slist, &scnt, t);
    __syncthreads();
    const int cnt = scnt;
    if (cnt == 0) return;

    const float* __restrict__ Mc = M + (size_t)c * HID * HID;
    const int wv = t >> 6, ln = t & 63;
    const int hg = t >> 4, jq = t & 15;

    if (t < 64) {
        const int jg = col0 + t;
        dj_lds[t] = fmaxf(Mc[(size_t)jg * HID + jg], 1e-3f);
    }

    for (int g0 = 0; g0 < cnt; g0 += SG) {
        const int gs = min(SG, cnt - g0);
        __syncthreads();                      // prev group done; dj_lds visible
        // stage x rows: wave wv stages samples 2wv, 2wv+1; also row-sums X
        #pragma unroll
        for (int ss = 0; ss < 2; ++ss) {
            const int s = 2 * wv + ss;
            const int b = slist[g0 + (s < gs ? s : 0)];
            const float4* xr = (const float4*)(x + (size_t)b * HID);
            const float4 v0 = xr[ln], v1 = xr[ln + 64], v2 = xr[ln + 128];
            *(float4*)&xs[s][ln * 4]       = v0;
            *(float4*)&xs[s][ln * 4 + 256] = v1;
            *(float4*)&xs[s][ln * 4 + 512] = v2;
            float pX = ((v0.x + v0.y) + (v0.z + v0.w))
                     + ((v1.x + v1.y) + (v1.z + v1.w))
                     + ((v2.x + v2.y) + (v2.z + v2.w));
            #pragma unroll
            for (int off = 32; off; off >>= 1) pX += __shfl_xor(pX, off);
            if (ln == 0) Xs[s] = pX;
        }
        __syncthreads();                      // xs, Xs visible

        float tp[4][SG];
        #pragma unroll
        for (int jj = 0; jj < 4; ++jj)
            #pragma unroll
            for (int s = 0; s < SG; ++s) tp[jj][s] = 0.f;

        for (int h = hg; h < col0 + 64; h += 16) {
            float4 mq = *(const float4*)(Mc + (size_t)h * HID + col0 + jq * 4);
            if (h >= col0) {                  // diagonal square: strict h<j
                const int hrel = h - col0;
                if (4 * jq + 0 <= hrel) mq.x = 0.f;
                if (4 * jq + 1 <= hrel) mq.y = 0.f;
                if (4 * jq + 2 <= hrel) mq.z = 0.f;
                if (4 * jq + 3 <= hrel) mq.w = 0.f;
            }
            #pragma unroll
            for (int s = 0; s < SG; ++s) {
                const float xv = xs[s][h];
                tp[0][s] = fmaf(xv, mq.x, tp[0][s]);
                tp[1][s] = fmaf(xv, mq.y, tp[1][s]);
                tp[2][s] = fmaf(xv, mq.z, tp[2][s]);
                tp[3][s] = fmaf(xv, mq.w, tp[3][s]);
            }
        }
        // reduce the 4 row-groups within each wave (lane bits 4,5)
        #pragma unroll
        for (int m = 16; m <= 32; m <<= 1)
            #pragma unroll
            for (int jj = 0; jj < 4; ++jj)
                #pragma unroll
                for (int s = 0; s < SG; ++s)
                    tp[jj][s] += __shfl_xor(tp[jj][s], m);
        if (ln < 16) {
            #pragma unroll
            for (int jj = 0; jj < 4; ++jj)
                #pragma unroll
                for (int s = 0; s < SG; ++s)
                    red[wv][ln][jj][s] = tp[jj][s];
        }
        __syncthreads();                      // red visible
        // finalize: thread t handles col j = t&63 for 2 samples
        {
            const int j = t & 63, jq2 = j >> 2, jj2 = j & 3;
            const int jg = col0 + j;
            #pragma unroll
            for (int ss = 0; ss < 2; ++ss) {
                const int s = (t >> 6) * 2 + ss;
                if (s < gs) {
                    const float u = (red[0][jq2][jj2][s] + red[1][jq2][jj2][s])
                                  + (red[2][jq2][jj2][s] + red[3][jq2][jj2][s]);
                    const float xj = xs[s][jg];
                    T[(size_t)slist[g0 + s] * HID + jg] =
                        u + dj_lds[j] * xj + 1e-3f * (Xs[s] - xj);
                }
            }
        }
    }
}

// ---------------------------------------------------------------------------
// Kernel B: out[b, k] for k in 64-row panel K=[64q, 64q+64), b in class c.
//   out_k = sum_{j>k} M[k,j] t_j + d_k t_k + 1e-3 (Tt - t_k)
// Row strip k in K, j >= k0, each row read 256 B contiguous.
// Thread map: kr = t>>4 (16 rows x 4 m-chunks), cg = t&15 (16 col-quads).
// q=0 (biggest) dispatches first.
// ---------------------------------------------------------------------------
__global__ __launch_bounds__(256, 4) void kB(
    const int* __restrict__ y, const float* __restrict__ M,
    const float* __restrict__ T, float* __restrict__ out)
{
    const int c  = blockIdx.x;
    const int q  = blockIdx.y;
    const int t  = threadIdx.x;
    const int k0 = q * 64;

    __shared__ int   slist[BATCH];
    __shared__ int   scnt;
    __shared__ float ts[SG][HID];         // 24 KB
    __shared__ float Tt[SG];
    __shared__ float ob[SG][64];          // 2 KB
    __shared__ float dk_lds[64];

    build_list(y, c, slist, &scnt, t);
    __syncthreads();
    const int cnt = scnt;
    if (cnt == 0) return;

    const float* __restrict__ Mc = M + (size_t)c * HID * HID;
    const int wv = t >> 6, ln = t & 63;
    const int kr = t >> 4, cg = t & 15;

    if (t < 64) {
        const int kg = k0 + t;
        dk_lds[t] = fmaxf(Mc[(size_t)kg * HID + kg], 1e-3f);
    }

    for (int g0 = 0; g0 < cnt; g0 += SG) {
        const int gs = min(SG, cnt - g0);
        __syncthreads();                      // prev group done (ob reads done)
        // stage t rows: wave wv stages samples 2wv, 2wv+1; also row-sums Tt
        #pragma unroll
        for (int ss = 0; ss < 2; ++ss) {
            const int s = 2 * wv + ss;
            const int b = slist[g0 + (s < gs ? s : 0)];
            const float4* tr = (const float4*)(T + (size_t)b * HID);
            const float4 v0 = tr[ln], v1 = tr[ln + 64], v2 = tr[ln + 128];
            *(float4*)&ts[s][ln * 4]       = v0;
            *(float4*)&ts[s][ln * 4 + 256] = v1;
            *(float4*)&ts[s][ln * 4 + 512] = v2;
            float pT = ((v0.x + v0.y) + (v0.z + v0.w))
                     + ((v1.x + v1.y) + (v1.z + v1.w))
                     + ((v2.x + v2.y) + (v2.z + v2.w));
            #pragma unroll
            for (int off = 32; off; off >>= 1) pT += __shfl_xor(pT, off);
            if (ln == 0) Tt[s] = pT;
        }
        __syncthreads();                      // ts, Tt visible

        float acc[4][SG];
        #pragma unroll
        for (int m = 0; m < 4; ++m)
            #pragma unroll
            for (int s = 0; s < SG; ++s) acc[m][s] = 0.f;

        for (int jb = k0; jb < HID; jb += 64) {
            const int j0 = jb + cg * 4;
            float4 mq[4];
            #pragma unroll
            for (int m = 0; m < 4; ++m) {
                const int k = k0 + 16 * m + kr;
                mq[m] = *(const float4*)(Mc + (size_t)k * HID + j0);
                if (jb == k0) {               // diag-crossing chunk: keep j>k
                    if (j0 + 0 <= k) mq[m].x = 0.f;
                    if (j0 + 1 <= k) mq[m].y = 0.f;
                    if (j0 + 2 <= k) mq[m].z = 0.f;
                    if (j0 + 3 <= k) mq[m].w = 0.f;
                }
            }
            #pragma unroll
            for (int s = 0; s < SG; ++s) {
                const float4 tv = *(const float4*)&ts[s][j0];
                #pragma unroll
                for (int m = 0; m < 4; ++m) {
                    acc[m][s] = fmaf(mq[m].x, tv.x, acc[m][s]);
                    acc[m][s] = fmaf(mq[m].y, tv.y, acc[m][s]);
                    acc[m][s] = fmaf(mq[m].z, tv.z, acc[m][s]);
                    acc[m][s] = fmaf(mq[m].w, tv.w, acc[m][s]);
                }
            }
        }
        // reduce over the 16 col-quads (lane bits 0..3)
        #pragma unroll
        for (int m2 = 1; m2 <= 8; m2 <<= 1)
            #pragma unroll
            for (int m = 0; m < 4; ++m)
                #pragma unroll
                for (int s = 0; s < SG; ++s)
                    acc[m][s] += __shfl_xor(acc[m][s], m2);
        if (cg == 0) {
            #pragma unroll
            for (int m = 0; m < 4; ++m)
                #pragma unroll
                for (int s = 0; s < SG; ++s)
                    ob[s][16 * m + kr] = acc[m][s];
        }
        __syncthreads();                      // ob visible
        // store: thread t handles k = k0 + (t&63) for 2 samples
        {
            const int j = t & 63;
            const int k = k0 + j;
            #pragma unroll
            for (int ss = 0; ss < 2; ++ss) {
                const int s = (t >> 6) * 2 + ss;
                if (s < gs) {
                    const float tk = ts[s][k];
                    out[(size_t)slist[g0 + s] * HID + k] =
                        ob[s][j] + dk_lds[j] * tk + 1e-3f * (Tt[s] - tk);
                }
            }
        }
    }
}

extern "C" void kernel_launch(void* const* d_in, const int* in_sizes, int n_in,
                              void* d_out, int out_size, void* d_ws, size_t ws_size,
                              hipStream_t stream) {
    const float* x = (const float*)d_in[0];
    const int*   y = (const int*)d_in[1];
    const float* M = (const float*)d_in[2];
    float* out = (float*)d_out;
    float* T   = (float*)d_ws;   // 512 * 768 * 4 B = 1.5 MiB scratch

    kA<<<dim3(NCLASS, NPAN), 256, 0, stream>>>(x, y, M, T);
    kB<<<dim3(NCLASS, NPAN), 256, 0, stream>>>(y, M, T, out);
}